// Round 22
// baseline (196.764 us; speedup 1.0000x reference)
//
#include <hip/hip_runtime.h>
#include <cmath>

typedef __bf16 bf16;
typedef bf16 bf16x8 __attribute__((ext_vector_type(8)));
typedef bf16 bf16x4 __attribute__((ext_vector_type(4)));
typedef float f32x4 __attribute__((ext_vector_type(4)));

#define MFMA __builtin_amdgcn_mfma_f32_16x16x32_bf16

constexpr int BB  = 4;
constexpr int CIN = 512;
constexpr int CC  = 128;
constexpr int NN  = 6272;        // 8*28*28
constexpr int NT  = NN / 32;     // 196 d-tiles of 32
constexpr int IT  = NN / 64;     // 98 64-row tiles

__device__ __forceinline__ void glds16(const void* g, void* l) {
    __builtin_amdgcn_global_load_lds(
        (const __attribute__((address_space(1))) unsigned int*)g,
        (__attribute__((address_space(3))) unsigned int*)l, 16, 0, 0);
}
#define WAIT_LGKM0 asm volatile("s_waitcnt lgkmcnt(0)" ::: "memory")
#define WAIT_VM0   asm volatile("s_waitcnt vmcnt(0)" ::: "memory")
#define WAIT_VM8   asm volatile("s_waitcnt vmcnt(8)" ::: "memory")
#define SBAR()     do { __builtin_amdgcn_s_barrier(); __builtin_amdgcn_sched_barrier(0); } while (0)

__device__ __forceinline__ float hw_exp2(float x) {
    float r;
    asm("v_exp_f32 %0, %1" : "=v"(r) : "v"(x));
    return r;
}

// ---------------------------------------------------------------------------
// Kernel 0: convert kw,qw,vw,rw f32 -> bf16 in ws.
// ---------------------------------------------------------------------------
__global__ __launch_bounds__(256) void k_wcvt(
    const float* __restrict__ kw, const float* __restrict__ qw,
    const float* __restrict__ vw, const float* __restrict__ rw,
    bf16* __restrict__ o)
{
    const int idx = (blockIdx.x * 256 + threadIdx.x) * 4;
    const float* s;
    if      (idx < 65536)  s = kw + idx;
    else if (idx < 131072) s = qw + (idx - 65536);
    else if (idx < 196608) s = vw + (idx - 131072);
    else                   s = rw + (idx - 196608);
    f32x4 v = *(const f32x4*)s;
    bf16* d = o + idx;
    d[0] = (bf16)v[0]; d[1] = (bf16)v[1]; d[2] = (bf16)v[2]; d[3] = (bf16)v[3];
}

// ---------------------------------------------------------------------------
// Kernel 1: K [b][n][128] plain; Q [b][n][128] granule-swizzled (j^=n&7)
// (for conflict-free linear glds staging in k_attn); V^T [b][128][n] plain.
// K/Q waves split as (proj, ot-pair): weight loads 4x amortized.
// ---------------------------------------------------------------------------
__global__ __launch_bounds__(512, 2) void k_kqv(
    const float* __restrict__ x,
    const bf16* __restrict__ wkb, const float* __restrict__ kbias,
    const bf16* __restrict__ wqb, const float* __restrict__ qbias,
    const bf16* __restrict__ wvb, const float* __restrict__ vbias,
    bf16* __restrict__ Kg, bf16* __restrict__ Qg, bf16* __restrict__ Vt)
{
    __shared__ bf16 xt[64 * 512];   // (n,c) -> xt[n*512 + (((c>>3)^(n&7))<<3) + (c&7)]
    const int b  = blockIdx.y;
    const int n0 = blockIdx.x * 64;
    const int t  = threadIdx.x;

    {   // stage x^T tile
        const int nl = t & 63;
        const int cg = t >> 6;
        const float* xp = x + (size_t)b * CIN * NN + n0 + nl;
        for (int c0 = cg * 8; c0 < CIN; c0 += 64) {
            bf16x8 pk;
            #pragma unroll
            for (int j = 0; j < 8; ++j) pk[j] = (bf16)xp[(size_t)(c0 + j) * NN];
            const int blk = ((c0 >> 3) ^ (nl & 7));
            *(bf16x8*)(&xt[nl * 512 + (blk << 3)]) = pk;
        }
    }
    __syncthreads();

    const int w  = t >> 6;
    const int ln = t & 63;
    const int lr = ln & 15;
    const int lg = ln >> 4;

    // ---- K and Q: wave = (proj h, ot-pair op); o = (op*2+oi)*16 + lr ----
    {
        const int h  = w >> 2;            // 0 = K, 1 = Q
        const int op = w & 3;             // which pair of output-col tiles
        const bf16* pw = h ? wqb : wkb;
        const float* pb = h ? qbias : kbias;
        bf16* dst = h ? Qg : Kg;
        f32x4 acc[4][2];
        #pragma unroll
        for (int ns = 0; ns < 4; ++ns)
            #pragma unroll
            for (int oi = 0; oi < 2; ++oi) acc[ns][oi] = f32x4{0.f, 0.f, 0.f, 0.f};
        for (int kk = 0; kk < 16; ++kk) {
            bf16x8 bw[2];
            #pragma unroll
            for (int oi = 0; oi < 2; ++oi)
                bw[oi] = *(const bf16x8*)(&pw[(size_t)((op * 2 + oi) * 16 + lr) * CIN + (kk << 5) + (lg << 3)]);
            #pragma unroll
            for (int ns = 0; ns < 4; ++ns) {
                const int nrow = ns * 16 + lr;
                bf16x8 a = *(const bf16x8*)(&xt[nrow * 512 + ((((kk << 2) + lg) ^ (nrow & 7)) << 3)]);
                acc[ns][0] = MFMA(a, bw[0], acc[ns][0], 0, 0, 0);
                acc[ns][1] = MFMA(a, bw[1], acc[ns][1], 0, 0, 0);
            }
        }
        #pragma unroll
        for (int ns = 0; ns < 4; ++ns)
            #pragma unroll
            for (int oi = 0; oi < 2; ++oi)
                #pragma unroll
                for (int r = 0; r < 4; ++r) {
                    const int n_ = n0 + ns * 16 + (lg << 2) + r;
                    const int o  = (op * 2 + oi) * 16 + lr;
                    const int oe = h ? ((((o >> 3) ^ (n_ & 7)) << 3) | (o & 7)) : o;
                    dst[((size_t)b * NN + n_) * CC + oe] = (bf16)(acc[ns][oi][r] + pb[o]);
                }
    }

    // ---- V^T (plain layout) ----
    {
        f32x4 vac[4];
        #pragma unroll
        for (int i = 0; i < 4; ++i) vac[i] = f32x4{0.f, 0.f, 0.f, 0.f};
        for (int kk = 0; kk < 16; ++kk) {
            bf16x8 a = *(const bf16x8*)(&wvb[(size_t)(w * 16 + lr) * CIN + (kk << 5) + (lg << 3)]);
            #pragma unroll
            for (int nt = 0; nt < 4; ++nt) {
                const int nrow = nt * 16 + lr;
                bf16x8 bfr = *(const bf16x8*)(&xt[nrow * 512 + ((((kk << 2) + lg) ^ (nrow & 7)) << 3)]);
                vac[nt] = MFMA(a, bfr, vac[nt], 0, 0, 0);
            }
        }
        #pragma unroll
        for (int nt = 0; nt < 4; ++nt)
            #pragma unroll
            for (int r = 0; r < 4; ++r) {
                const int o  = w * 16 + (lg << 2) + r;
                const int n_ = n0 + nt * 16 + lr;
                Vt[((size_t)b * CC + o) * NN + n_] = (bf16)(vac[nt][r] + vbias[o]);
            }
    }
}

// ---------------------------------------------------------------------------
// Kernel 2: fused batch-softmax attention — WAVE-SPECIALIZED, Q staging
// FLIPPED onto the PV waves (who idle at the barrier): the critical QK
// chain is now completely VMEM-free inside the loop (no glds issue, no
// vmcnt drain, no scheduler pin).
//   Waves 0..3 (QK): kf for 2 i-subs, ds_read Q frags -> MFMA -> softmax ->
//     packed b64 P-write -> lgkm0 -> barrier. Zero vmem in the loop.
//   Waves 4..7 (PV): stage 8KB Q slice for t+1, pa reads, PV MFMA,
//     V global->reg, lgkm0 + vmcnt(8) (drains the 8 glds — oldest in the
//     in-order VMEM counter — while the 8 younger V loads stay in flight,
//     the R13-proven counted-drain trick) -> barrier.
// Same Qs/Ps double-buffer invariants as R17/R19, roles flipped.
// glds = latency firewall (twice-proven irreplaceable, R11/R15).
// ---------------------------------------------------------------------------
__global__ __launch_bounds__(512, 2) void k_attn(
    const bf16* __restrict__ Kg, const bf16* __restrict__ Qg,
    const bf16* __restrict__ Vt, bf16* __restrict__ midp,
    int dch, int tpc, float scl2)
{
    extern __shared__ char smem[];
    bf16* Qs = (bf16*)smem;                    // [2][4b*32d][128c] (granule-swz)
    bf16* Ps = (bf16*)(smem + 65536);          // [2][4b*64i][32d] granule^=(row>>1)&3

    const int bid = blockIdx.x;
    const int dc  = bid / IT;
    const int i0  = (bid % IT) * 64;
    const int t   = threadIdx.x;
    const int w   = t >> 6, ln = t & 63, lr = ln & 15, lg = ln >> 4;

    const int t_lo = dc * tpc;
    const int t_hi = min(t_lo + tpc, NT);

    int buf = 0, pbuf = 0;

    if (w < 4) {
        // ================= QK + softmax waves (VMEM-free loop) =============
        const int ch = w & 1, iq = w >> 1;
        bf16x8 kf[2][4][4];
        #pragma unroll
        for (int ws2 = 0; ws2 < 2; ++ws2)
            #pragma unroll
            for (int b = 0; b < 4; ++b)
                #pragma unroll
                for (int kk = 0; kk < 4; ++kk)
                    kf[ws2][b][kk] = *(const bf16x8*)(&Kg[((size_t)b * NN + i0 + (iq * 2 + ws2) * 16 + lr) * CC + (kk << 5) + (lg << 3)]);

        SBAR();              // matches PV prologue barrier (Qs[0] staged)

        const int d_  = ch * 16 + lr;
        const int dsw = lr & 7;

        for (int tt = t_lo; tt < t_hi; ++tt) {
            bf16* Qb = Qs + buf * 16384;
            f32x4 sa[2][4];
            #pragma unroll
            for (int ws2 = 0; ws2 < 2; ++ws2)
                #pragma unroll
                for (int b = 0; b < 4; ++b) sa[ws2][b] = f32x4{0.f, 0.f, 0.f, 0.f};
            __builtin_amdgcn_s_setprio(1);
            #pragma unroll
            for (int b = 0; b < 4; ++b) {
                const int row = b * 32 + d_;
                #pragma unroll
                for (int kk = 0; kk < 4; ++kk) {
                    bf16x8 qf = *(const bf16x8*)(&Qb[row * 128 + ((((kk << 2) + lg) ^ dsw) << 3)]);
                    sa[0][b] = MFMA(qf, kf[0][b][kk], sa[0][b], 0, 0, 0);
                    sa[1][b] = MFMA(qf, kf[1][b][kk], sa[1][b], 0, 0, 0);
                }
            }
            __builtin_amdgcn_s_setprio(0);

            #pragma unroll
            for (int ws2 = 0; ws2 < 2; ++ws2) {
                float p[4][4];
                #pragma unroll
                for (int r = 0; r < 4; ++r) {
                    const float e0 = hw_exp2(sa[ws2][0][r] * scl2);
                    const float e1 = hw_exp2(sa[ws2][1][r] * scl2);
                    const float e2 = hw_exp2(sa[ws2][2][r] * scl2);
                    const float e3 = hw_exp2(sa[ws2][3][r] * scl2);
                    const float rs = __builtin_amdgcn_rcpf(e0 + e1 + e2 + e3);
                    p[0][r] = e0 * rs; p[1][r] = e1 * rs; p[2][r] = e2 * rs; p[3][r] = e3 * rs;
                }
                const int row  = (iq * 2 + ws2) * 16 + lr;
                const int colg = (ch << 1) | (lg >> 1);       // d>>3
                const int sub  = (lg & 1) << 2;               // d&7 base (r=0)
                #pragma unroll
                for (int b = 0; b < 4; ++b) {
                    const int rw_ = b * 64 + row;
                    bf16x4 pk;
                    pk[0] = (bf16)p[b][0]; pk[1] = (bf16)p[b][1];
                    pk[2] = (bf16)p[b][2]; pk[3] = (bf16)p[b][3];
                    *(bf16x4*)(&Ps[pbuf * 8192 + rw_ * 32 + ((colg ^ ((rw_ >> 1) & 3)) << 3) + sub]) = pk;
                }
            }

            WAIT_LGKM0;      // P visible to all (and own Q ds_reads drained)
            SBAR();
            buf ^= 1; pbuf ^= 1;
        }
    } else {
        // ======= PV waves (stage Q for t+1 in their slack; counted drain) ==
        const int ww = w - 4;            // 0..3: staging slice + batch role
        const char* qsrc[8];
        #pragma unroll
        for (int i = 0; i < 8; ++i) {
            const int row = ((ww * 8 + i) << 2) + (ln >> 4);      // 0..127
            qsrc[i] = (const char*)Qg + (((size_t)(row >> 5) * NN + (row & 31)) * CC + (ln & 15) * 8) * 2;
        }
        auto stage = [&](int bf, int tile) {
            const size_t qoff = (size_t)tile * 8192;   // 32 rows * 256B
            char* qb = smem + bf * 32768 + ww * 8192;
            #pragma unroll
            for (int i = 0; i < 8; ++i) glds16(qsrc[i] + qoff, qb + i * 1024);
        };

        stage(0, t_lo);
        WAIT_VM0;
        SBAR();

        const int pb = ww;
        const bf16* vbase[8];
        #pragma unroll
        for (int ct = 0; ct < 8; ++ct)
            vbase[ct] = Vt + ((size_t)pb * CC + ct * 16 + lr) * NN + (lg << 3);

        f32x4 oacc[4][8];
        #pragma unroll
        for (int mt = 0; mt < 4; ++mt)
            #pragma unroll
            for (int ct = 0; ct < 8; ++ct) oacc[mt][ct] = f32x4{0.f, 0.f, 0.f, 0.f};

        bf16x8 vfp[8];
        for (int tt = t_lo; tt < t_hi; ++tt) {
            if (tt + 1 < t_hi) stage(buf ^ 1, tt + 1);
            __builtin_amdgcn_sched_barrier(0);       // pin: glds issue first

            if (tt > t_lo) {
                const bf16* Pr = Ps + (pbuf ^ 1) * 8192;
                bf16x8 pan[4];
                #pragma unroll
                for (int mt = 0; mt < 4; ++mt) {
                    const int prow = pb * 64 + mt * 16 + lr;
                    pan[mt] = *(const bf16x8*)(&Pr[prow * 32 + ((lg ^ ((prow >> 1) & 3)) << 3)]);
                }
                __builtin_amdgcn_s_setprio(1);
                #pragma unroll
                for (int mt = 0; mt < 4; ++mt)
                    #pragma unroll
                    for (int ct = 0; ct < 8; ++ct)
                        oacc[mt][ct] = MFMA(pan[mt], vfp[ct], oacc[mt][ct], 0, 0, 0);
                __builtin_amdgcn_s_setprio(0);
            }

            // ---- V(tt) global->reg into vfp (issued AFTER the glds, so the
            //      counted vmcnt(8) below leaves them in flight) ----
            #pragma unroll
            for (int ct = 0; ct < 8; ++ct)
                vfp[ct] = *(const bf16x8*)(vbase[ct] + tt * 32);

            WAIT_LGKM0;      // own pa reads drained
            WAIT_VM8;        // 8 glds (oldest) drained; 8 V loads in flight
            SBAR();
            buf ^= 1; pbuf ^= 1;
        }

        {   // epilogue: PV(t_hi-1)
            const bf16* Pr = Ps + (pbuf ^ 1) * 8192;
            bf16x8 pan[4];
            #pragma unroll
            for (int mt = 0; mt < 4; ++mt) {
                const int prow = pb * 64 + mt * 16 + lr;
                pan[mt] = *(const bf16x8*)(&Pr[prow * 32 + ((lg ^ ((prow >> 1) & 3)) << 3)]);
            }
            #pragma unroll
            for (int mt = 0; mt < 4; ++mt)
                #pragma unroll
                for (int ct = 0; ct < 8; ++ct)
                    oacc[mt][ct] = MFMA(pan[mt], vfp[ct], oacc[mt][ct], 0, 0, 0);
        }

        #pragma unroll
        for (int mt = 0; mt < 4; ++mt)
            #pragma unroll
            for (int ct = 0; ct < 8; ++ct)
                #pragma unroll
                for (int r = 0; r < 4; ++r) {
                    const int n_ = i0 + mt * 16 + (lg << 2) + r;
                    const int c  = ct * 16 + lr;
                    midp[(((size_t)dc * 4 + pb) * NN + n_) * CC + c] = (bf16)oacc[mt][ct][r];
                }
    }
}

// ---------------------------------------------------------------------------
// Kernel 3 (fused reduce + output GEMM, LDS-staged ONCE):
// red[n][c] = sum_dc midp[dc][b][n][c]  (coalesced reads, granule-XOR LDS)
// out[b][o][n] = sum_c rwb[o][c] * red[n][c] + rb[o]
// ---------------------------------------------------------------------------
__global__ __launch_bounds__(512, 2) void k_out2(
    const bf16* __restrict__ midp, const bf16* __restrict__ rwb,
    const float* __restrict__ rb, float* __restrict__ out, int dch)
{
    __shared__ bf16 red[64 * 128];   // (n,c) -> red[n*128 + (((c>>3)^(n&7))<<3) + (c&7)]
    const int b  = blockIdx.y;
    const int n0 = blockIdx.x * 64;
    const int t  = threadIdx.x;
    const int w  = t >> 6, ln = t & 63, lr = ln & 15, lg = ln >> 4;

    const size_t dstride = (size_t)BB * NN * CC;

    // ---- reduction pass: 8192 elems / 512 thr = 2 bf16x8 chunks each ----
    #pragma unroll
    for (int j2 = 0; j2 < 2; ++j2) {
        const int j  = t * 2 + j2;        // granule index 0..1023
        const int n  = j >> 4;            // 0..63
        const int cg = j & 15;            // granule 0..15
        const bf16* mp = midp + ((size_t)b * NN + n0 + n) * CC + (cg << 3);
        float s[8] = {0.f, 0.f, 0.f, 0.f, 0.f, 0.f, 0.f, 0.f};
        for (int d = 0; d < dch; ++d) {
            bf16x8 v = *(const bf16x8*)(mp + (size_t)d * dstride);
            #pragma unroll
            for (int k = 0; k < 8; ++k) s[k] += (float)v[k];
        }
        bf16x8 o;
        #pragma unroll
        for (int k = 0; k < 8; ++k) o[k] = (bf16)s[k];
        *(bf16x8*)(&red[n * 128 + ((cg ^ (n & 7)) << 3)]) = o;
    }
    __syncthreads();

    // ---- GEMM pass: B-fragments from LDS ----
    f32x4 acc[4][4];
    #pragma unroll
    for (int mt = 0; mt < 4; ++mt)
        #pragma unroll
        for (int nt = 0; nt < 4; ++nt) acc[mt][nt] = f32x4{0.f, 0.f, 0.f, 0.f};

    for (int kk = 0; kk < 4; ++kk) {
        bf16x8 bfr[4];
        #pragma unroll
        for (int nt = 0; nt < 4; ++nt) {
            const int n_ = nt * 16 + lr;
            const int cg = (kk << 2) + lg;
            bfr[nt] = *(const bf16x8*)(&red[n_ * 128 + ((cg ^ (n_ & 7)) << 3)]);
        }
        #pragma unroll
        for (int mt = 0; mt < 4; ++mt) {
            const int o = w * 64 + mt * 16 + lr;
            bf16x8 af = *(const bf16x8*)(&rwb[(size_t)o * CC + (kk << 5) + (lg << 3)]);
            #pragma unroll
            for (int nt = 0; nt < 4; ++nt)
                acc[mt][nt] = MFMA(af, bfr[nt], acc[mt][nt], 0, 0, 0);
        }
    }
    #pragma unroll
    for (int mt = 0; mt < 4; ++mt)
        #pragma unroll
        for (int nt = 0; nt < 4; ++nt)
            #pragma unroll
            for (int r = 0; r < 4; ++r) {
                const int o  = w * 64 + mt * 16 + (lg << 2) + r;
                const int n_ = n0 + nt * 16 + lr;
                out[((size_t)b * CIN + o) * NN + n_] = acc[mt][nt][r] + rb[o];
            }
}

// ---------------------------------------------------------------------------
extern "C" void kernel_launch(void* const* d_in, const int* in_sizes, int n_in,
                              void* d_out, int out_size, void* d_ws, size_t ws_size,
                              hipStream_t stream)
{
    const float* x  = (const float*)d_in[0];
    const float* kw = (const float*)d_in[1];
    const float* kb = (const float*)d_in[2];
    const float* qw = (const float*)d_in[3];
    const float* qb = (const float*)d_in[4];
    const float* vw = (const float*)d_in[5];
    const float* vb = (const float*)d_in[6];
    const float* rw = (const float*)d_in[7];
    const float* rb = (const float*)d_in[8];
    float* out = (float*)d_out;

    const size_t szP = (size_t)BB * NN * CC;      // 3,211,264 elements
    char* ws = (char*)d_ws;
    bf16* wkb = (bf16*)ws;                         // 512 KB of bf16 weights
    bf16* wqb = wkb + 65536;
    bf16* wvb = wqb + 65536;
    bf16* rwb = wvb + 65536;
    bf16* Kg  = (bf16*)(ws + 524288);
    bf16* Qg  = Kg + szP;
    bf16* Vt  = Qg + szP;
    const size_t base = 524288 + 3 * szP * sizeof(bf16);
    bf16* midp = (bf16*)(ws + base);

    // dch=5: same grid-utilization as 10 (95.7%), half the midp traffic.
    int dch = 1;
    if      (base + 5 * szP * sizeof(bf16) <= ws_size) dch = 5;
    else if (base + 4 * szP * sizeof(bf16) <= ws_size) dch = 4;
    else if (base + 2 * szP * sizeof(bf16) <= ws_size) dch = 2;

    const float scl2 = 1.4426950408889634f / sqrtf((float)NN);

    k_wcvt<<<dim3(256), 256, 0, stream>>>(kw, qw, vw, rw, wkb);

    k_kqv<<<dim3(IT, BB), 512, 0, stream>>>(x, wkb, kb, wqb, qb, wvb, vb, Kg, Qg, Vt);

    const int tpc = (NT + dch - 1) / dch;
    const size_t lds = 98304;   // 64K Qs (2 bufs) + 32K Ps (2 bufs)
    (void)hipFuncSetAttribute((const void*)k_attn,
                              hipFuncAttributeMaxDynamicSharedMemorySize, (int)lds);
    k_attn<<<dim3(IT * dch), 512, lds, stream>>>(Kg, Qg, Vt, midp, dch, tpc, scl2);

    k_out2<<<dim3(IT, BB), 512, 0, stream>>>(midp, rwb, rb, out, dch);
}

// Round 23
// 172.004 us; speedup vs baseline: 1.1440x; 1.1440x over previous
//
#include <hip/hip_runtime.h>
#include <cmath>

typedef __bf16 bf16;
typedef bf16 bf16x8 __attribute__((ext_vector_type(8)));
typedef bf16 bf16x4 __attribute__((ext_vector_type(4)));
typedef float f32x4 __attribute__((ext_vector_type(4)));

#define MFMA __builtin_amdgcn_mfma_f32_16x16x32_bf16

constexpr int BB  = 4;
constexpr int CIN = 512;
constexpr int CC  = 128;
constexpr int NN  = 6272;        // 8*28*28
constexpr int NT  = NN / 32;     // 196 d-tiles of 32
constexpr int IT  = NN / 64;     // 98 64-row tiles

__device__ __forceinline__ void glds16(const void* g, void* l) {
    __builtin_amdgcn_global_load_lds(
        (const __attribute__((address_space(1))) unsigned int*)g,
        (__attribute__((address_space(3))) unsigned int*)l, 16, 0, 0);
}
#define WAIT_LGKM0 asm volatile("s_waitcnt lgkmcnt(0)" ::: "memory")
#define WAIT_VM0   asm volatile("s_waitcnt vmcnt(0)" ::: "memory")
#define SBAR()     do { __builtin_amdgcn_s_barrier(); __builtin_amdgcn_sched_barrier(0); } while (0)

__device__ __forceinline__ float hw_exp2(float x) {
    float r;
    asm("v_exp_f32 %0, %1" : "=v"(r) : "v"(x));
    return r;
}

// ---------------------------------------------------------------------------
// Kernel 0: convert kw,qw,vw,rw f32 -> bf16 in ws.
// ---------------------------------------------------------------------------
__global__ __launch_bounds__(256) void k_wcvt(
    const float* __restrict__ kw, const float* __restrict__ qw,
    const float* __restrict__ vw, const float* __restrict__ rw,
    bf16* __restrict__ o)
{
    const int idx = (blockIdx.x * 256 + threadIdx.x) * 4;
    const float* s;
    if      (idx < 65536)  s = kw + idx;
    else if (idx < 131072) s = qw + (idx - 65536);
    else if (idx < 196608) s = vw + (idx - 131072);
    else                   s = rw + (idx - 196608);
    f32x4 v = *(const f32x4*)s;
    bf16* d = o + idx;
    d[0] = (bf16)v[0]; d[1] = (bf16)v[1]; d[2] = (bf16)v[2]; d[3] = (bf16)v[3];
}

// ---------------------------------------------------------------------------
// Kernel 1: K [b][n][128] plain; Q [b][n][128] granule-swizzled (j^=n&7)
// (for conflict-free linear glds staging in k_attn); V^T [b][128][n] plain.
// K/Q waves split as (proj, ot-pair): weight loads 4x amortized.
// ---------------------------------------------------------------------------
__global__ __launch_bounds__(512, 2) void k_kqv(
    const float* __restrict__ x,
    const bf16* __restrict__ wkb, const float* __restrict__ kbias,
    const bf16* __restrict__ wqb, const float* __restrict__ qbias,
    const bf16* __restrict__ wvb, const float* __restrict__ vbias,
    bf16* __restrict__ Kg, bf16* __restrict__ Qg, bf16* __restrict__ Vt)
{
    __shared__ bf16 xt[64 * 512];   // (n,c) -> xt[n*512 + (((c>>3)^(n&7))<<3) + (c&7)]
    const int b  = blockIdx.y;
    const int n0 = blockIdx.x * 64;
    const int t  = threadIdx.x;

    {   // stage x^T tile
        const int nl = t & 63;
        const int cg = t >> 6;
        const float* xp = x + (size_t)b * CIN * NN + n0 + nl;
        for (int c0 = cg * 8; c0 < CIN; c0 += 64) {
            bf16x8 pk;
            #pragma unroll
            for (int j = 0; j < 8; ++j) pk[j] = (bf16)xp[(size_t)(c0 + j) * NN];
            const int blk = ((c0 >> 3) ^ (nl & 7));
            *(bf16x8*)(&xt[nl * 512 + (blk << 3)]) = pk;
        }
    }
    __syncthreads();

    const int w  = t >> 6;
    const int ln = t & 63;
    const int lr = ln & 15;
    const int lg = ln >> 4;

    // ---- K and Q: wave = (proj h, ot-pair op); o = (op*2+oi)*16 + lr ----
    {
        const int h  = w >> 2;            // 0 = K, 1 = Q
        const int op = w & 3;             // which pair of output-col tiles
        const bf16* pw = h ? wqb : wkb;
        const float* pb = h ? qbias : kbias;
        bf16* dst = h ? Qg : Kg;
        f32x4 acc[4][2];
        #pragma unroll
        for (int ns = 0; ns < 4; ++ns)
            #pragma unroll
            for (int oi = 0; oi < 2; ++oi) acc[ns][oi] = f32x4{0.f, 0.f, 0.f, 0.f};
        for (int kk = 0; kk < 16; ++kk) {
            bf16x8 bw[2];
            #pragma unroll
            for (int oi = 0; oi < 2; ++oi)
                bw[oi] = *(const bf16x8*)(&pw[(size_t)((op * 2 + oi) * 16 + lr) * CIN + (kk << 5) + (lg << 3)]);
            #pragma unroll
            for (int ns = 0; ns < 4; ++ns) {
                const int nrow = ns * 16 + lr;
                bf16x8 a = *(const bf16x8*)(&xt[nrow * 512 + ((((kk << 2) + lg) ^ (nrow & 7)) << 3)]);
                acc[ns][0] = MFMA(a, bw[0], acc[ns][0], 0, 0, 0);
                acc[ns][1] = MFMA(a, bw[1], acc[ns][1], 0, 0, 0);
            }
        }
        #pragma unroll
        for (int ns = 0; ns < 4; ++ns)
            #pragma unroll
            for (int oi = 0; oi < 2; ++oi)
                #pragma unroll
                for (int r = 0; r < 4; ++r) {
                    const int n_ = n0 + ns * 16 + (lg << 2) + r;
                    const int o  = (op * 2 + oi) * 16 + lr;
                    const int oe = h ? ((((o >> 3) ^ (n_ & 7)) << 3) | (o & 7)) : o;
                    dst[((size_t)b * NN + n_) * CC + oe] = (bf16)(acc[ns][oi][r] + pb[o]);
                }
    }

    // ---- V^T (plain layout) ----
    {
        f32x4 vac[4];
        #pragma unroll
        for (int i = 0; i < 4; ++i) vac[i] = f32x4{0.f, 0.f, 0.f, 0.f};
        for (int kk = 0; kk < 16; ++kk) {
            bf16x8 a = *(const bf16x8*)(&wvb[(size_t)(w * 16 + lr) * CIN + (kk << 5) + (lg << 3)]);
            #pragma unroll
            for (int nt = 0; nt < 4; ++nt) {
                const int nrow = nt * 16 + lr;
                bf16x8 bfr = *(const bf16x8*)(&xt[nrow * 512 + ((((kk << 2) + lg) ^ (nrow & 7)) << 3)]);
                vac[nt] = MFMA(a, bfr, vac[nt], 0, 0, 0);
            }
        }
        #pragma unroll
        for (int nt = 0; nt < 4; ++nt)
            #pragma unroll
            for (int r = 0; r < 4; ++r) {
                const int o  = w * 16 + (lg << 2) + r;
                const int n_ = n0 + nt * 16 + lr;
                Vt[((size_t)b * CC + o) * NN + n_] = (bf16)(vac[nt][r] + vbias[o]);
            }
    }
}

// ---------------------------------------------------------------------------
// Kernel 2: fused batch-softmax attention — FINAL (R17/R19 proven, 126 µs).
// WAVE-SPECIALIZED with Q staging entirely on QK waves (PV waves have zero
// glds -> no vmcnt at their barrier, fully decoupled from the VMEM queue).
//   Waves 0..3 (QK): (ch = w&1 d-half, iq = w>>1 i-pair), kf for 2 i-subs,
//     stage 8KB Q slice, softmax in-register, packed b64 P-write,
//     lgkm0 + vm0 drain (covers all staging) + barrier.
//   Waves 4..7 (PV): pb = w-4, full 128-c PV, oacc[4][8], V global->reg,
//     lgkm0 + barrier only.
// glds = latency firewall (twice-proven irreplaceable, R11/R15); staging
// lives on the LONG (QK) chain whose compute covers the drain (R22 lesson).
// ---------------------------------------------------------------------------
__global__ __launch_bounds__(512, 2) void k_attn(
    const bf16* __restrict__ Kg, const bf16* __restrict__ Qg,
    const bf16* __restrict__ Vt, bf16* __restrict__ midp,
    int dch, int tpc, float scl2)
{
    extern __shared__ char smem[];
    bf16* Qs = (bf16*)smem;                    // [2][4b*32d][128c] (granule-swz)
    bf16* Ps = (bf16*)(smem + 65536);          // [2][4b*64i][32d] granule^=(row>>1)&3

    const int bid = blockIdx.x;
    const int dc  = bid / IT;
    const int i0  = (bid % IT) * 64;
    const int t   = threadIdx.x;
    const int w   = t >> 6, ln = t & 63, lr = ln & 15, lg = ln >> 4;

    const int t_lo = dc * tpc;
    const int t_hi = min(t_lo + tpc, NT);

    int buf = 0, pbuf = 0;

    if (w < 4) {
        // ================= QK + softmax waves (also sole Q stagers) ========
        const char* qsrc[8];
        #pragma unroll
        for (int i = 0; i < 8; ++i) {
            const int row = ((w * 8 + i) << 2) + (ln >> 4);       // 0..127
            qsrc[i] = (const char*)Qg + (((size_t)(row >> 5) * NN + (row & 31)) * CC + (ln & 15) * 8) * 2;
        }
        auto stage = [&](int bf, int tile) {
            const size_t qoff = (size_t)tile * 8192;   // 32 rows * 256B
            char* qb = smem + bf * 32768 + w * 8192;
            #pragma unroll
            for (int i = 0; i < 8; ++i) glds16(qsrc[i] + qoff, qb + i * 1024);
        };

        stage(0, t_lo);
        WAIT_VM0;
        SBAR();

        const int ch = w & 1, iq = w >> 1;
        bf16x8 kf[2][4][4];
        #pragma unroll
        for (int ws2 = 0; ws2 < 2; ++ws2)
            #pragma unroll
            for (int b = 0; b < 4; ++b)
                #pragma unroll
                for (int kk = 0; kk < 4; ++kk)
                    kf[ws2][b][kk] = *(const bf16x8*)(&Kg[((size_t)b * NN + i0 + (iq * 2 + ws2) * 16 + lr) * CC + (kk << 5) + (lg << 3)]);

        const int d_  = ch * 16 + lr;
        const int dsw = lr & 7;

        for (int tt = t_lo; tt < t_hi; ++tt) {
            if (tt + 1 < t_hi) stage(buf ^ 1, tt + 1);
            __builtin_amdgcn_sched_barrier(0);       // pin: glds issue first

            bf16* Qb = Qs + buf * 16384;
            f32x4 sa[2][4];
            #pragma unroll
            for (int ws2 = 0; ws2 < 2; ++ws2)
                #pragma unroll
                for (int b = 0; b < 4; ++b) sa[ws2][b] = f32x4{0.f, 0.f, 0.f, 0.f};
            __builtin_amdgcn_s_setprio(1);
            #pragma unroll
            for (int b = 0; b < 4; ++b) {
                const int row = b * 32 + d_;
                #pragma unroll
                for (int kk = 0; kk < 4; ++kk) {
                    bf16x8 qf = *(const bf16x8*)(&Qb[row * 128 + ((((kk << 2) + lg) ^ dsw) << 3)]);
                    sa[0][b] = MFMA(qf, kf[0][b][kk], sa[0][b], 0, 0, 0);
                    sa[1][b] = MFMA(qf, kf[1][b][kk], sa[1][b], 0, 0, 0);
                }
            }
            __builtin_amdgcn_s_setprio(0);

            #pragma unroll
            for (int ws2 = 0; ws2 < 2; ++ws2) {
                float p[4][4];
                #pragma unroll
                for (int r = 0; r < 4; ++r) {
                    const float e0 = hw_exp2(sa[ws2][0][r] * scl2);
                    const float e1 = hw_exp2(sa[ws2][1][r] * scl2);
                    const float e2 = hw_exp2(sa[ws2][2][r] * scl2);
                    const float e3 = hw_exp2(sa[ws2][3][r] * scl2);
                    const float rs = __builtin_amdgcn_rcpf(e0 + e1 + e2 + e3);
                    p[0][r] = e0 * rs; p[1][r] = e1 * rs; p[2][r] = e2 * rs; p[3][r] = e3 * rs;
                }
                const int row  = (iq * 2 + ws2) * 16 + lr;
                const int colg = (ch << 1) | (lg >> 1);       // d>>3
                const int sub  = (lg & 1) << 2;               // d&7 base (r=0)
                #pragma unroll
                for (int b = 0; b < 4; ++b) {
                    const int rw_ = b * 64 + row;
                    bf16x4 pk;
                    pk[0] = (bf16)p[b][0]; pk[1] = (bf16)p[b][1];
                    pk[2] = (bf16)p[b][2]; pk[3] = (bf16)p[b][3];
                    *(bf16x4*)(&Ps[pbuf * 8192 + rw_ * 32 + ((colg ^ ((rw_ >> 1) & 3)) << 3) + sub]) = pk;
                }
            }

            WAIT_LGKM0;      // P visible to all
            WAIT_VM0;        // own 8 glds (issued at iter top) drained
            SBAR();
            buf ^= 1; pbuf ^= 1;
        }
    } else {
        // ================= PV waves (no glds, no vmcnt coupling) ==========
        SBAR();              // matches QK prologue barrier

        const int pb = w - 4;
        const bf16* vbase[8];
        #pragma unroll
        for (int ct = 0; ct < 8; ++ct)
            vbase[ct] = Vt + ((size_t)pb * CC + ct * 16 + lr) * NN + (lg << 3);

        f32x4 oacc[4][8];
        #pragma unroll
        for (int mt = 0; mt < 4; ++mt)
            #pragma unroll
            for (int ct = 0; ct < 8; ++ct) oacc[mt][ct] = f32x4{0.f, 0.f, 0.f, 0.f};

        bf16x8 vfp[8];
        for (int tt = t_lo; tt < t_hi; ++tt) {
            if (tt > t_lo) {
                const bf16* Pr = Ps + (pbuf ^ 1) * 8192;
                bf16x8 pan[4];
                #pragma unroll
                for (int mt = 0; mt < 4; ++mt) {
                    const int prow = pb * 64 + mt * 16 + lr;
                    pan[mt] = *(const bf16x8*)(&Pr[prow * 32 + ((lg ^ ((prow >> 1) & 3)) << 3)]);
                }
                __builtin_amdgcn_s_setprio(1);
                #pragma unroll
                for (int mt = 0; mt < 4; ++mt)
                    #pragma unroll
                    for (int ct = 0; ct < 8; ++ct)
                        oacc[mt][ct] = MFMA(pan[mt], vfp[ct], oacc[mt][ct], 0, 0, 0);
                __builtin_amdgcn_s_setprio(0);
            }

            // ---- V(tt) global->reg into vfp (consumed next window; WAR
            //      ordered by scoreboard, no explicit wait needed) ----
            #pragma unroll
            for (int ct = 0; ct < 8; ++ct)
                vfp[ct] = *(const bf16x8*)(vbase[ct] + tt * 32);

            WAIT_LGKM0;      // own pa reads drained (already consumed — cheap)
            SBAR();
            buf ^= 1; pbuf ^= 1;
        }

        {   // epilogue: PV(t_hi-1)
            const bf16* Pr = Ps + (pbuf ^ 1) * 8192;
            bf16x8 pan[4];
            #pragma unroll
            for (int mt = 0; mt < 4; ++mt) {
                const int prow = pb * 64 + mt * 16 + lr;
                pan[mt] = *(const bf16x8*)(&Pr[prow * 32 + ((lg ^ ((prow >> 1) & 3)) << 3)]);
            }
            #pragma unroll
            for (int mt = 0; mt < 4; ++mt)
                #pragma unroll
                for (int ct = 0; ct < 8; ++ct)
                    oacc[mt][ct] = MFMA(pan[mt], vfp[ct], oacc[mt][ct], 0, 0, 0);
        }

        #pragma unroll
        for (int mt = 0; mt < 4; ++mt)
            #pragma unroll
            for (int ct = 0; ct < 8; ++ct)
                #pragma unroll
                for (int r = 0; r < 4; ++r) {
                    const int n_ = i0 + mt * 16 + (lg << 2) + r;
                    const int c  = ct * 16 + lr;
                    midp[(((size_t)dc * 4 + pb) * NN + n_) * CC + c] = (bf16)oacc[mt][ct][r];
                }
    }
}

// ---------------------------------------------------------------------------
// Kernel 3 (fused reduce + output GEMM, LDS-staged ONCE):
// red[n][c] = sum_dc midp[dc][b][n][c]  (coalesced reads, granule-XOR LDS)
// out[b][o][n] = sum_c rwb[o][c] * red[n][c] + rb[o]
// ---------------------------------------------------------------------------
__global__ __launch_bounds__(512, 2) void k_out2(
    const bf16* __restrict__ midp, const bf16* __restrict__ rwb,
    const float* __restrict__ rb, float* __restrict__ out, int dch)
{
    __shared__ bf16 red[64 * 128];   // (n,c) -> red[n*128 + (((c>>3)^(n&7))<<3) + (c&7)]
    const int b  = blockIdx.y;
    const int n0 = blockIdx.x * 64;
    const int t  = threadIdx.x;
    const int w  = t >> 6, ln = t & 63, lr = ln & 15, lg = ln >> 4;

    const size_t dstride = (size_t)BB * NN * CC;

    // ---- reduction pass: 8192 elems / 512 thr = 2 bf16x8 chunks each ----
    #pragma unroll
    for (int j2 = 0; j2 < 2; ++j2) {
        const int j  = t * 2 + j2;        // granule index 0..1023
        const int n  = j >> 4;            // 0..63
        const int cg = j & 15;            // granule 0..15
        const bf16* mp = midp + ((size_t)b * NN + n0 + n) * CC + (cg << 3);
        float s[8] = {0.f, 0.f, 0.f, 0.f, 0.f, 0.f, 0.f, 0.f};
        for (int d = 0; d < dch; ++d) {
            bf16x8 v = *(const bf16x8*)(mp + (size_t)d * dstride);
            #pragma unroll
            for (int k = 0; k < 8; ++k) s[k] += (float)v[k];
        }
        bf16x8 o;
        #pragma unroll
        for (int k = 0; k < 8; ++k) o[k] = (bf16)s[k];
        *(bf16x8*)(&red[n * 128 + ((cg ^ (n & 7)) << 3)]) = o;
    }
    __syncthreads();

    // ---- GEMM pass: B-fragments from LDS ----
    f32x4 acc[4][4];
    #pragma unroll
    for (int mt = 0; mt < 4; ++mt)
        #pragma unroll
        for (int nt = 0; nt < 4; ++nt) acc[mt][nt] = f32x4{0.f, 0.f, 0.f, 0.f};

    for (int kk = 0; kk < 4; ++kk) {
        bf16x8 bfr[4];
        #pragma unroll
        for (int nt = 0; nt < 4; ++nt) {
            const int n_ = nt * 16 + lr;
            const int cg = (kk << 2) + lg;
            bfr[nt] = *(const bf16x8*)(&red[n_ * 128 + ((cg ^ (n_ & 7)) << 3)]);
        }
        #pragma unroll
        for (int mt = 0; mt < 4; ++mt) {
            const int o = w * 64 + mt * 16 + lr;
            bf16x8 af = *(const bf16x8*)(&rwb[(size_t)o * CC + (kk << 5) + (lg << 3)]);
            #pragma unroll
            for (int nt = 0; nt < 4; ++nt)
                acc[mt][nt] = MFMA(af, bfr[nt], acc[mt][nt], 0, 0, 0);
        }
    }
    #pragma unroll
    for (int mt = 0; mt < 4; ++mt)
        #pragma unroll
        for (int nt = 0; nt < 4; ++nt)
            #pragma unroll
            for (int r = 0; r < 4; ++r) {
                const int o  = w * 64 + mt * 16 + (lg << 2) + r;
                const int n_ = n0 + nt * 16 + lr;
                out[((size_t)b * CIN + o) * NN + n_] = acc[mt][nt][r] + rb[o];
            }
}

// ---------------------------------------------------------------------------
extern "C" void kernel_launch(void* const* d_in, const int* in_sizes, int n_in,
                              void* d_out, int out_size, void* d_ws, size_t ws_size,
                              hipStream_t stream)
{
    const float* x  = (const float*)d_in[0];
    const float* kw = (const float*)d_in[1];
    const float* kb = (const float*)d_in[2];
    const float* qw = (const float*)d_in[3];
    const float* qb = (const float*)d_in[4];
    const float* vw = (const float*)d_in[5];
    const float* vb = (const float*)d_in[6];
    const float* rw = (const float*)d_in[7];
    const float* rb = (const float*)d_in[8];
    float* out = (float*)d_out;

    const size_t szP = (size_t)BB * NN * CC;      // 3,211,264 elements
    char* ws = (char*)d_ws;
    bf16* wkb = (bf16*)ws;                         // 512 KB of bf16 weights
    bf16* wqb = wkb + 65536;
    bf16* wvb = wqb + 65536;
    bf16* rwb = wvb + 65536;
    bf16* Kg  = (bf16*)(ws + 524288);
    bf16* Qg  = Kg + szP;
    bf16* Vt  = Qg + szP;
    const size_t base = 524288 + 3 * szP * sizeof(bf16);
    bf16* midp = (bf16*)(ws + base);

    // dch=5: same grid-utilization as 10 (95.7%), half the midp traffic.
    int dch = 1;
    if      (base + 5 * szP * sizeof(bf16) <= ws_size) dch = 5;
    else if (base + 4 * szP * sizeof(bf16) <= ws_size) dch = 4;
    else if (base + 2 * szP * sizeof(bf16) <= ws_size) dch = 2;

    const float scl2 = 1.4426950408889634f / sqrtf((float)NN);

    k_wcvt<<<dim3(256), 256, 0, stream>>>(kw, qw, vw, rw, wkb);

    k_kqv<<<dim3(IT, BB), 512, 0, stream>>>(x, wkb, kb, wqb, qb, wvb, vb, Kg, Qg, Vt);

    const int tpc = (NT + dch - 1) / dch;
    const size_t lds = 98304;   // 64K Qs (2 bufs) + 32K Ps (2 bufs)
    (void)hipFuncSetAttribute((const void*)k_attn,
                              hipFuncAttributeMaxDynamicSharedMemorySize, (int)lds);
    k_attn<<<dim3(IT * dch), 512, lds, stream>>>(Kg, Qg, Vt, midp, dch, tpc, scl2);

    k_out2<<<dim3(IT, BB), 512, 0, stream>>>(midp, rwb, rb, out, dch);
}